// Round 18
// baseline (130.094 us; speedup 1.0000x reference)
//
#include <hip/hip_runtime.h>
#include <stdint.h>

typedef unsigned short u16;
typedef unsigned long long u64;
typedef __attribute__((ext_vector_type(8))) short short8;
typedef __attribute__((ext_vector_type(4))) float f32x4;

#define MFMA16 __builtin_amdgcn_mfma_f32_16x16x32_bf16

#define MTOT 65536   // B*N = 1024*64

__device__ __forceinline__ u16 f2bf(float f) {
  union { float f; uint32_t u; } v; v.f = f;
  uint32_t r = v.u + 0x7FFFu + ((v.u >> 16) & 1u);
  return (u16)(r >> 16);
}

union U8 { short8 v; u16 u[8]; };
union U4 { u64 v; u16 u[4]; };

__device__ __forceinline__ void cp16(const void* g, void* l) {
  __builtin_amdgcn_global_load_lds(
      (const __attribute__((address_space(1))) void*)g,
      (__attribute__((address_space(3))) void*)l, 16, 0, 0);
}

// 64-B-row LDS swizzle: chunk ^= (row>>1)&3
__device__ __forceinline__ int swz(int row) { return ((row >> 1) & 3) << 4; }

// ---------------------------------------------------------------------------
// L1: prep1 (0..255) + wconv W1,W2,Wq,Wk (256..367) + adj bitmask (368..1391)
// ---------------------------------------------------------------------------
__global__ __launch_bounds__(256) void k_l1(
    const float* __restrict__ Wc, const float* __restrict__ Wo,
    const float* __restrict__ bo, const float* __restrict__ bc,
    float* __restrict__ M1, float* __restrict__ bv,
    const float* __restrict__ W1, const float* __restrict__ W2,
    const float* __restrict__ Wq, const float* __restrict__ Wk,
    u16* o1, u16* o2, u16* oq, u16* ok,
    const float* __restrict__ adj, u64* __restrict__ adjm_g) {
  const int bid = blockIdx.x, tid = threadIdx.x;
  if (bid < 256) {
    __shared__ float wcr[256];
    __shared__ float red[4];
    const int j = bid, d = tid;
    wcr[d] = Wc[j * 256 + d];
    __syncthreads();
    float acc = 0.f;
#pragma unroll 8
    for (int i = 0; i < 256; i++) acc += wcr[i] * Wo[i * 256 + d];
    M1[j * 256 + d] = acc;
    float p = wcr[d] * bo[d];
    for (int off = 32; off >= 1; off >>= 1) p += __shfl_xor(p, off);
    if ((d & 63) == 0) red[d >> 6] = p;
    __syncthreads();
    if (d == 0) bv[j] = bc[j] + red[0] + red[1] + red[2] + red[3];
  } else if (bid < 368) {
    int off8 = (bid - 256) * 256 + tid;
    const float* src; u16* dst;
    if      (off8 <  4096) { src = W1; dst = o1; }
    else if (off8 < 12288) { src = W2; dst = o2; off8 -= 4096; }
    else if (off8 < 20480) { src = Wq; dst = oq; off8 -= 12288; }
    else                   { src = Wk; dst = ok; off8 -= 20480; }
    const int e = off8 * 8;
    f32x4 a = *(const f32x4*)(src + e);
    f32x4 b = *(const f32x4*)(src + e + 4);
    U8 pk;
#pragma unroll
    for (int j = 0; j < 4; j++) { pk.u[j] = f2bf(a[j]); pk.u[4 + j] = f2bf(b[j]); }
    *(short8*)(dst + e) = pk.v;
  } else {
    __shared__ u16 chunk[64][4];
    const int b = bid - 368;
    const int q = tid >> 2, qa = tid & 3;
    const float* ar = adj + ((size_t)b * 64 + q) * 64 + qa * 16;
    f32x4 a0 = *(const f32x4*)(ar);
    f32x4 a1 = *(const f32x4*)(ar + 4);
    f32x4 a2 = *(const f32x4*)(ar + 8);
    f32x4 a3 = *(const f32x4*)(ar + 12);
    unsigned m16 = 0;
#pragma unroll
    for (int i = 0; i < 4; i++) {
      m16 |= (unsigned)(a0[i] != 0.f) << i;
      m16 |= (unsigned)(a1[i] != 0.f) << (4 + i);
      m16 |= (unsigned)(a2[i] != 0.f) << (8 + i);
      m16 |= (unsigned)(a3[i] != 0.f) << (12 + i);
    }
    chunk[q][qa] = (u16)m16;
    __syncthreads();
    if (tid < 64)
      adjm_g[(size_t)b * 64 + tid] =
          (u64)chunk[tid][0] | ((u64)chunk[tid][1] << 16) |
          ((u64)chunk[tid][2] << 32) | ((u64)chunk[tid][3] << 48);
  }
}

// ---------------------------------------------------------------------------
// gemm_full2<K,AF32,VZ>: C[m0:+128, 0:256] = act(A@W^T + b) -> bf16.
// BK=32 dbuf; non-AF32 counted-vmcnt pipeline; AF32 plain barrier loop.
// LDS-staged coalesced epilogue. VZ: additionally compute
// Vz[m0:+128, 0:64] = act(C) @ G[64,256]^T from the Cs staging buffer.
// [Do NOT tighten launch_bounds: 128 acc VGPRs spill below (256,2).]
// ---------------------------------------------------------------------------
template<int K, bool AF32, bool VZ>
__device__ __forceinline__ void gemm_full2(
    const void* __restrict__ Ain, const u16* __restrict__ W,
    const float* __restrict__ bias, u16* __restrict__ C,
    const int m0, const bool relu, char* smem,
    const u16* __restrict__ Gw, u16* __restrict__ Vzt) {
  const int tid = threadIdx.x;
  const int lane = tid & 63, wid = tid >> 6;
  const int wr = wid >> 1, wc = wid & 1;
  const int ro = lane & 15, hi = lane >> 4;

  f32x4 acc0[4][4], acc1[4][4];
#pragma unroll
  for (int m = 0; m < 4; m++)
#pragma unroll
    for (int n = 0; n < 4; n++) {
      acc0[m][n] = (f32x4){0.f, 0.f, 0.f, 0.f};
      acc1[m][n] = (f32x4){0.f, 0.f, 0.f, 0.f};
    }
  f32x4 vzacc[2][4];
  if (VZ) {
#pragma unroll
    for (int h = 0; h < 2; h++)
#pragma unroll
      for (int cf = 0; cf < 4; cf++) vzacc[h][cf] = (f32x4){0.f, 0.f, 0.f, 0.f};
  }

  auto stage = [&](int buf, int k0) {
    char* Ax = smem + buf * 24576;
    char* Bx = Ax + 8192;
    if (AF32) {
      const float* Af = (const float*)Ain;
#pragma unroll
      for (int it = 0; it < 2; it++) {
        const int e = (tid + it * 256) * 8;
        const int r = e >> 5, c = e & 31;
        const float* s = Af + (size_t)(m0 + r) * K + k0 + c;
        f32x4 a = *(const f32x4*)s, b = *(const f32x4*)(s + 4);
        U8 pk;
#pragma unroll
        for (int j = 0; j < 4; j++) { pk.u[j] = f2bf(a[j]); pk.u[4 + j] = f2bf(b[j]); }
        *(short8*)(Ax + ((r * 64 + c * 2) ^ swz(r))) = pk.v;
      }
    } else {
      const u16* Ab = (const u16*)Ain;
#pragma unroll
      for (int i = 0; i < 2; i++) {
        const int boff = i * 4096 + wid * 1024;
        const int t = boff + lane * 16;
        const int row = t >> 6;
        const int cb = (t & 63) ^ swz(row);
        cp16(Ab + (size_t)(m0 + row) * K + k0 + (cb >> 1), Ax + boff);
      }
    }
#pragma unroll
    for (int i = 0; i < 4; i++) {
      const int boff = i * 4096 + wid * 1024;
      const int t = boff + lane * 16;
      const int row = t >> 6;
      const int cb = (t & 63) ^ swz(row);
      cp16(W + (size_t)row * K + k0 + (cb >> 1), Bx + boff);
    }
  };

  auto compute = [&](int buf) {
    char* Ax = smem + buf * 24576;
    char* Bx = Ax + 8192;
    short8 af[4], fb0[4], fb1[4];
#pragma unroll
    for (int m = 0; m < 4; m++) {
      const int row = wr * 64 + m * 16 + ro;
      af[m] = *(const short8*)(Ax + ((row * 64 + hi * 16) ^ swz(row)));
    }
#pragma unroll
    for (int n = 0; n < 4; n++) {
      const int r0 = wc * 64 + n * 16 + ro;
      fb0[n] = *(const short8*)(Bx + ((r0 * 64 + hi * 16) ^ swz(r0)));
      const int r1 = 128 + r0;
      fb1[n] = *(const short8*)(Bx + ((r1 * 64 + hi * 16) ^ swz(r1)));
    }
    __builtin_amdgcn_s_setprio(1);
#pragma unroll
    for (int m = 0; m < 4; m++)
#pragma unroll
      for (int n = 0; n < 4; n++) {
        acc0[m][n] = MFMA16(af[m], fb0[n], acc0[m][n], 0, 0, 0);
        acc1[m][n] = MFMA16(af[m], fb1[n], acc1[m][n], 0, 0, 0);
      }
    __builtin_amdgcn_s_setprio(0);
  };

  constexpr int NT = K / 32;
  if (AF32) {
    stage(0, 0);
    __syncthreads();
    int cur = 0;
    for (int k0 = 32; k0 < K; k0 += 32) {
      stage(cur ^ 1, k0);
      compute(cur);
      __syncthreads();
      cur ^= 1;
    }
    compute(cur);
    __syncthreads();
  } else {
    stage(0, 0);
    stage(1, 32);
#pragma unroll
    for (int t = 0; t < NT; ++t) {
      if (t == NT - 1) asm volatile("s_waitcnt vmcnt(0)" ::: "memory");
      else             asm volatile("s_waitcnt vmcnt(6)" ::: "memory");
      asm volatile("s_barrier" ::: "memory");
      compute(t & 1);
      asm volatile("s_barrier" ::: "memory");
      if (t + 2 < NT) stage(t & 1, (t + 2) * 32);
    }
  }

  u16 (*Cs)[136] = (u16(*)[136])smem;   // 17.4 KB
  char* Gl = smem + 18432;              // VZ: G[64][128] bf16 swizzled, 16 KB
  auto ep = [&](f32x4 (&acc)[4][4], const int n0) {
    if (VZ) {
#pragma unroll
      for (int i = 0; i < 4; i++) {
        const int boff = i * 4096 + wid * 1024;
        const int t = boff + lane * 16;
        const int row = t >> 8;
        const int cb = (t & 255) ^ ((row & 7) << 4);
        cp16(Gw + (size_t)row * 256 + n0 + (cb >> 1), Gl + boff);
      }
    }
#pragma unroll
    for (int half = 0; half < 2; half++) {
      if (wr == half) {
#pragma unroll
        for (int n = 0; n < 4; n++) {
          const int col = wc * 64 + n * 16 + ro;
          const float bb = bias[n0 + col];
#pragma unroll
          for (int m = 0; m < 4; m++)
#pragma unroll
            for (int j = 0; j < 4; j++) {
              float val = acc[m][n][j] + bb;
              if (relu) val = fmaxf(val, 0.f);
              Cs[m * 16 + hi * 4 + j][col] = f2bf(val);
            }
        }
      }
      __syncthreads();   // Cs visible; drains G-stage cp16s too
      for (int i = tid; i < 64 * 16; i += 256) {
        const int r = i >> 4, c = (i & 15) << 3;
        *(short8*)(C + (size_t)(m0 + half * 64 + r) * 256 + n0 + c) = *(short8*)&Cs[r][c];
      }
      if (VZ) {
#pragma unroll
        for (int ks = 0; ks < 4; ks++) {
          short8 af = *(const short8*)&Cs[wid * 16 + ro][ks * 32 + hi * 8];
#pragma unroll
          for (int cf = 0; cf < 4; cf++) {
            const int c = cf * 16 + ro;
            short8 gb = *(const short8*)(Gl + ((c * 256 + (ks * 32 + hi * 8) * 2) ^ ((c & 7) << 4)));
            vzacc[half][cf] = MFMA16(af, gb, vzacc[half][cf], 0, 0, 0);
          }
        }
      }
      __syncthreads();
    }
  };
  ep(acc0, 0);
  ep(acc1, 128);

  if (VZ) {
#pragma unroll
    for (int half = 0; half < 2; half++) {
      const int bidx = (m0 >> 6) + half;
      const int ke = wid * 16 + hi * 4;
#pragma unroll
      for (int cf = 0; cf < 4; cf++) {
        const int c = cf * 16 + ro;
        U4 pk;
#pragma unroll
        for (int j = 0; j < 4; j++) pk.u[j] = f2bf(vzacc[half][cf][j]);
        *(u64*)(Vzt + (size_t)bidx * 4096 + (size_t)c * 64 + ke) = pk.v;
      }
    }
  }
}

// ---------------------------------------------------------------------------
// L2: gemm1 (blocks 0..511, K=128, AF32) + prep2+prep3 merged (512..527)
// ---------------------------------------------------------------------------
__global__ __launch_bounds__(256, 2) void k_gemm1_prep2(
    const float* __restrict__ obs, const u16* __restrict__ W1b,
    const float* __restrict__ b1, u16* __restrict__ x1,
    const float* __restrict__ W3, const float* __restrict__ M1,
    const float* __restrict__ bvchain, const float* __restrict__ bvw,
    const float* __restrict__ Wv, u16* __restrict__ G,
    float* __restrict__ bz) {
  __shared__ char smem[49152];
  if (blockIdx.x < 512) {
    gemm_full2<128, true, false>(obs, W1b, b1, x1, (int)blockIdx.x * 128,
                                 true, smem, nullptr, nullptr);
    return;
  }
  float* w3r = (float*)smem;
  float* wzs = (float*)(smem + 1024);
  float* red = (float*)(smem + 2048);
  const int a = blockIdx.x - 512, d = threadIdx.x;
  w3r[d] = W3[a * 256 + d];
  __syncthreads();
  float acc = 0.f;
#pragma unroll 8
  for (int j = 0; j < 256; j++) acc += w3r[j] * M1[j * 256 + d];
  wzs[d] = acc;                       // Wzf row a
  float p = w3r[d] * bvchain[d] + acc * bvw[d];
  for (int off = 32; off >= 1; off >>= 1) p += __shfl_xor(p, off);
  if ((d & 63) == 0) red[d >> 6] = p;
  __syncthreads();                    // wzs + red ready
  if (d == 0) bz[a] = red[0] + red[1] + red[2] + red[3];
#pragma unroll
  for (int h = 0; h < 4; h++) {
    float g = 0.f;
#pragma unroll 8
    for (int d2 = 0; d2 < 64; d2++)
      g += wzs[h * 64 + d2] * Wv[(size_t)(h * 64 + d2) * 256 + d];
    G[(size_t)(h * 16 + a) * 256 + d] = f2bf(g);
  }
}

// ---------------------------------------------------------------------------
// L3: x2 = relu(x1@W2^T+b2) + fused Vz = x2@G^T (blocks 0..511)
// ---------------------------------------------------------------------------
__global__ __launch_bounds__(256, 2) void k_x2_vz(
    const u16* __restrict__ x1, const u16* __restrict__ W2b,
    const float* __restrict__ b2, u16* __restrict__ x2,
    const u16* __restrict__ G, u16* __restrict__ Vzt) {
  __shared__ char smem[49152];
  gemm_full2<256, false, true>(x1, W2b, b2, x2, (int)blockIdx.x * 128,
                               true, smem, G, Vzt);
}

// ---------------------------------------------------------------------------
// L4: Q/K full-row tiles, XCD-paired (blocks 0..1023)
// ---------------------------------------------------------------------------
__global__ __launch_bounds__(256, 2) void k_qk(
    const u16* __restrict__ x2,
    const u16* __restrict__ Wqb, const float* __restrict__ bq, u16* __restrict__ Qg,
    const u16* __restrict__ Wkb, const float* __restrict__ bk, u16* __restrict__ Kg) {
  __shared__ char smem[49152];
  const int bid = blockIdx.x;
  const int q = bid >> 4, r = bid & 15;
  const int mt = q * 8 + (r & 7);
  const int sub = r >> 3;
  gemm_full2<256, false, false>(x2, sub ? Wkb : Wqb, sub ? bk : bq,
                                sub ? Kg : Qg, mt * 128, false, smem,
                                nullptr, nullptr);
}

// ---------------------------------------------------------------------------
// attn_fused: per b. QK^T -> masked in-register softmax -> P@Vz ->
// cross-head Z reduce -> out = adj@Z + b3 + deg*bz. adjm precomputed (L1).
// Zs overlays Ps (PV in regs + barrier): LDS 37.4 KB.
// ---------------------------------------------------------------------------
__global__ __launch_bounds__(256, 2) void attn_fused(
    const u16* __restrict__ Qg, const u16* __restrict__ Kg,
    const u16* __restrict__ Vzt, const u64* __restrict__ adjm_g,
    const float* __restrict__ bz, const float* __restrict__ b3,
    float* __restrict__ out) {
  __shared__ char sm_raw[36864];
  __shared__ u64 adjm[64];
  u16 (*Ps)[64][72] = (u16(*)[64][72])sm_raw;
  float (*Zs)[64][16] = (float(*)[64][16])sm_raw;

  const int b = blockIdx.x, tid = threadIdx.x;
  const int lane = tid & 63, w = tid >> 6;
  const int ro = lane & 15, hi = lane >> 4;
  const int hc = w * 64;
  const size_t base = (size_t)b * 64 * 256;

  if (tid < 64) adjm[tid] = adjm_g[(size_t)b * 64 + tid];

  short8 kb[4][2];
#pragma unroll
  for (int n = 0; n < 4; n++)
#pragma unroll
    for (int ks = 0; ks < 2; ks++)
      kb[n][ks] = *(const short8*)(Kg + base + (size_t)(n * 16 + ro) * 256 + hc + ks * 32 + hi * 8);

  f32x4 s[4][4];
#pragma unroll
  for (int m = 0; m < 4; m++) {
    short8 af[2];
#pragma unroll
    for (int ks = 0; ks < 2; ks++)
      af[ks] = *(const short8*)(Qg + base + (size_t)(m * 16 + ro) * 256 + hc + ks * 32 + hi * 8);
#pragma unroll
    for (int n = 0; n < 4; n++) s[m][n] = (f32x4){0.f, 0.f, 0.f, 0.f};
#pragma unroll
    for (int ks = 0; ks < 2; ks++)
#pragma unroll
      for (int n = 0; n < 4; n++)
        s[m][n] = MFMA16(af[ks], kb[n][ks], s[m][n], 0, 0, 0);
  }

  short8 vz[2];
#pragma unroll
  for (int ks = 0; ks < 2; ks++)
    vz[ks] = *(const short8*)(Vzt + (size_t)b * 4096 + (size_t)(hc / 4 + ro) * 64 + ks * 32 + hi * 8);

  __syncthreads();   // adjm ready

#pragma unroll
  for (int m = 0; m < 4; m++) {
#pragma unroll
    for (int j = 0; j < 4; j++) {
      const int q = m * 16 + hi * 4 + j;
      const u64 msk = adjm[q];
      float sv[4], ev[4];
      float mx = -3.0e38f;
#pragma unroll
      for (int n = 0; n < 4; n++) {
        const bool on = (msk >> (n * 16 + ro)) & 1ull;
        sv[n] = on ? s[m][n][j] * 0.125f : -3.0e38f;
        mx = fmaxf(mx, sv[n]);
      }
      mx = fmaxf(mx, __shfl_xor(mx, 1));
      mx = fmaxf(mx, __shfl_xor(mx, 2));
      mx = fmaxf(mx, __shfl_xor(mx, 4));
      mx = fmaxf(mx, __shfl_xor(mx, 8));
      float sum = 0.f;
#pragma unroll
      for (int n = 0; n < 4; n++) {
        ev[n] = (sv[n] > -1.0e37f) ? __expf(sv[n] - mx) : 0.f;
        sum += ev[n];
      }
      sum += __shfl_xor(sum, 1);
      sum += __shfl_xor(sum, 2);
      sum += __shfl_xor(sum, 4);
      sum += __shfl_xor(sum, 8);
      const float inv = 1.0f / sum;
#pragma unroll
      for (int n = 0; n < 4; n++)
        Ps[w][q][n * 16 + ro] = f2bf(ev[n] * inv);
    }
  }

  f32x4 oz[4];
#pragma unroll
  for (int m = 0; m < 4; m++) {
    short8 pa[2];
    pa[0] = *(const short8*)&Ps[w][m * 16 + ro][hi * 8];
    pa[1] = *(const short8*)&Ps[w][m * 16 + ro][32 + hi * 8];
    oz[m] = (f32x4){0.f, 0.f, 0.f, 0.f};
#pragma unroll
    for (int ks = 0; ks < 2; ks++)
      oz[m] = MFMA16(pa[ks], vz[ks], oz[m], 0, 0, 0);
  }
  __syncthreads();

#pragma unroll
  for (int m = 0; m < 4; m++)
#pragma unroll
    for (int j = 0; j < 4; j++)
      Zs[w][m * 16 + hi * 4 + j][ro] = oz[m][j];
  __syncthreads();

  for (int i = tid; i < 1024; i += 256) {
    const int r = i >> 4, a = i & 15;
    Zs[0][r][a] += Zs[1][r][a] + Zs[2][r][a] + Zs[3][r][a];
  }
  __syncthreads();

  {
    const int n = tid >> 2, a4 = (tid & 3) << 2;
    const u64 msk = adjm[n];
    const float deg = (float)__popcll(msk);
    float a0 = 0.f, a1 = 0.f, a2 = 0.f, a3 = 0.f;
#pragma unroll 8
    for (int m = 0; m < 64; m++) {
      const float wv = (float)((msk >> m) & 1ull);
      f32x4 z = *(const f32x4*)&Zs[0][m][a4];
      a0 += wv * z[0]; a1 += wv * z[1]; a2 += wv * z[2]; a3 += wv * z[3];
    }
    f32x4 r;
    r[0] = a0 + b3[a4 + 0] + deg * bz[a4 + 0];
    r[1] = a1 + b3[a4 + 1] + deg * bz[a4 + 1];
    r[2] = a2 + b3[a4 + 2] + deg * bz[a4 + 2];
    r[3] = a3 + b3[a4 + 3] + deg * bz[a4 + 3];
    *(f32x4*)(out + ((size_t)b * 64 + n) * 16 + a4) = r;
  }
}

// ---------------------------------------------------------------------------
extern "C" void kernel_launch(void* const* d_in, const int* in_sizes, int n_in,
                              void* d_out, int out_size, void* d_ws, size_t ws_size,
                              hipStream_t stream) {
  const float* obs = (const float*)d_in[0];
  const float* adj = (const float*)d_in[1];
  const float* W1  = (const float*)d_in[2];
  const float* b1  = (const float*)d_in[3];
  const float* W2  = (const float*)d_in[4];
  const float* b2  = (const float*)d_in[5];
  const float* Wq  = (const float*)d_in[6];
  const float* bq  = (const float*)d_in[7];
  const float* Wk  = (const float*)d_in[8];
  const float* bk  = (const float*)d_in[9];
  const float* Wv  = (const float*)d_in[10];
  const float* bvw = (const float*)d_in[11];
  const float* Wo  = (const float*)d_in[12];
  const float* bo  = (const float*)d_in[13];
  const float* Wc  = (const float*)d_in[14];
  const float* bc  = (const float*)d_in[15];
  const float* W3  = (const float*)d_in[16];
  const float* b3  = (const float*)d_in[17];
  float* out = (float*)d_out;

  char* ws = (char*)d_ws;
  const size_t BIG = (size_t)MTOT * 256 * 2;       // 33.5 MB
  u16* buf0 = (u16*)(ws);                          // x1
  u16* buf1 = (u16*)(ws + BIG);                    // x2
  u16* buf2 = (u16*)(ws + 2 * BIG);                // Q
  u16* buf3 = (u16*)(ws + 3 * BIG);                // K
  char* p = ws + 4 * BIG;
  u16* W1b = (u16*)p;              p += 128 * 256 * 2;
  u16* W2b = (u16*)p;              p += 256 * 256 * 2;
  u16* Wqb = (u16*)p;              p += 256 * 256 * 2;
  u16* Wkb = (u16*)p;              p += 256 * 256 * 2;
  float* M1 = (float*)p;           p += 256 * 256 * 4;
  u16* G   = (u16*)p;              p += 64 * 256 * 2;
  float* bv = (float*)p;           p += 256 * 4;
  float* bz = (float*)p;           p += 16 * 4;
  u64* adjm_g = (u64*)p;           p += (size_t)MTOT * 8;        // 512 KB
  u16* Vzt = (u16*)p;              p += (size_t)MTOT * 64 * 2;   // 8.4 MB

  dim3 blk(256);
  k_l1<<<dim3(1392), blk, 0, stream>>>(Wc, Wo, bo, bc, M1, bv,
                                       W1, W2, Wq, Wk, W1b, W2b, Wqb, Wkb,
                                       adj, adjm_g);
  k_gemm1_prep2<<<dim3(528), blk, 0, stream>>>(obs, W1b, b1, buf0,
                                               W3, M1, bv, bvw, Wv, G, bz);
  k_x2_vz<<<dim3(512), blk, 0, stream>>>(buf0, W2b, b2, buf1, G, Vzt);
  k_qk<<<dim3(1024), blk, 0, stream>>>(buf1, Wqb, bq, buf2, Wkb, bk, buf3);
  attn_fused<<<dim3(1024), blk, 0, stream>>>(buf2, buf3, Vzt, adjm_g, bz, b3, out);
}

// Round 19
// 125.032 us; speedup vs baseline: 1.0405x; 1.0405x over previous
//
#include <hip/hip_runtime.h>
#include <stdint.h>

typedef unsigned short u16;
typedef unsigned long long u64;
typedef __attribute__((ext_vector_type(8))) short short8;
typedef __attribute__((ext_vector_type(4))) float f32x4;

#define MFMA16 __builtin_amdgcn_mfma_f32_16x16x32_bf16

#define MTOT 65536   // B*N = 1024*64

__device__ __forceinline__ u16 f2bf(float f) {
  union { float f; uint32_t u; } v; v.f = f;
  uint32_t r = v.u + 0x7FFFu + ((v.u >> 16) & 1u);
  return (u16)(r >> 16);
}

union U8 { short8 v; u16 u[8]; };
union U4 { u64 v; u16 u[4]; };

__device__ __forceinline__ void cp16(const void* g, void* l) {
  __builtin_amdgcn_global_load_lds(
      (const __attribute__((address_space(1))) void*)g,
      (__attribute__((address_space(3))) void*)l, 16, 0, 0);
}

// 64-B-row LDS swizzle: chunk ^= (row>>1)&3
__device__ __forceinline__ int swz(int row) { return ((row >> 1) & 3) << 4; }

// ---------------------------------------------------------------------------
// L1: prep1 (0..255) + wconv W1,W2,Wq,Wk (256..367) + adj bitmask (368..1391)
// ---------------------------------------------------------------------------
__global__ __launch_bounds__(256) void k_l1(
    const float* __restrict__ Wc, const float* __restrict__ Wo,
    const float* __restrict__ bo, const float* __restrict__ bc,
    float* __restrict__ M1, float* __restrict__ bv,
    const float* __restrict__ W1, const float* __restrict__ W2,
    const float* __restrict__ Wq, const float* __restrict__ Wk,
    u16* o1, u16* o2, u16* oq, u16* ok,
    const float* __restrict__ adj, u64* __restrict__ adjm_g) {
  const int bid = blockIdx.x, tid = threadIdx.x;
  if (bid < 256) {
    __shared__ float wcr[256];
    __shared__ float red[4];
    const int j = bid, d = tid;
    wcr[d] = Wc[j * 256 + d];
    __syncthreads();
    float acc = 0.f;
#pragma unroll 8
    for (int i = 0; i < 256; i++) acc += wcr[i] * Wo[i * 256 + d];
    M1[j * 256 + d] = acc;
    float p = wcr[d] * bo[d];
    for (int off = 32; off >= 1; off >>= 1) p += __shfl_xor(p, off);
    if ((d & 63) == 0) red[d >> 6] = p;
    __syncthreads();
    if (d == 0) bv[j] = bc[j] + red[0] + red[1] + red[2] + red[3];
  } else if (bid < 368) {
    int off8 = (bid - 256) * 256 + tid;
    const float* src; u16* dst;
    if      (off8 <  4096) { src = W1; dst = o1; }
    else if (off8 < 12288) { src = W2; dst = o2; off8 -= 4096; }
    else if (off8 < 20480) { src = Wq; dst = oq; off8 -= 12288; }
    else                   { src = Wk; dst = ok; off8 -= 20480; }
    const int e = off8 * 8;
    f32x4 a = *(const f32x4*)(src + e);
    f32x4 b = *(const f32x4*)(src + e + 4);
    U8 pk;
#pragma unroll
    for (int j = 0; j < 4; j++) { pk.u[j] = f2bf(a[j]); pk.u[4 + j] = f2bf(b[j]); }
    *(short8*)(dst + e) = pk.v;
  } else {
    __shared__ u16 chunk[64][4];
    const int b = bid - 368;
    const int q = tid >> 2, qa = tid & 3;
    const float* ar = adj + ((size_t)b * 64 + q) * 64 + qa * 16;
    f32x4 a0 = *(const f32x4*)(ar);
    f32x4 a1 = *(const f32x4*)(ar + 4);
    f32x4 a2 = *(const f32x4*)(ar + 8);
    f32x4 a3 = *(const f32x4*)(ar + 12);
    unsigned m16 = 0;
#pragma unroll
    for (int i = 0; i < 4; i++) {
      m16 |= (unsigned)(a0[i] != 0.f) << i;
      m16 |= (unsigned)(a1[i] != 0.f) << (4 + i);
      m16 |= (unsigned)(a2[i] != 0.f) << (8 + i);
      m16 |= (unsigned)(a3[i] != 0.f) << (12 + i);
    }
    chunk[q][qa] = (u16)m16;
    __syncthreads();
    if (tid < 64)
      adjm_g[(size_t)b * 64 + tid] =
          (u64)chunk[tid][0] | ((u64)chunk[tid][1] << 16) |
          ((u64)chunk[tid][2] << 32) | ((u64)chunk[tid][3] << 48);
  }
}

// ---------------------------------------------------------------------------
// gemm_full2<K,AF32,VZ>: C[m0:+128, 0:256] = act(A@W^T + b) -> bf16.
// BK=32 dbuf; non-AF32 counted-vmcnt pipeline; AF32 plain barrier loop.
// LDS-staged coalesced epilogue. VZ (Q-blocks of L4): additionally compute
// Vz[m0:+128, 0:64] = A @ G[64,256]^T riding the SAME staged A tiles:
// G[64x32] tile staged per K-step (dbuf at smem+49152, +1 cp16 -> vmcnt 7),
// 8 extra MFMA/wave/K-step into vzacc[4][2], transposed u64 store after loop.
// [Do NOT tighten launch_bounds: 128+ acc VGPRs spill below (256,2).]
// ---------------------------------------------------------------------------
template<int K, bool AF32, bool VZ>
__device__ __forceinline__ void gemm_full2(
    const void* __restrict__ Ain, const u16* __restrict__ W,
    const float* __restrict__ bias, u16* __restrict__ C,
    const int m0, const bool relu, char* smem,
    const u16* __restrict__ Gw, u16* __restrict__ Vzt) {
  const int tid = threadIdx.x;
  const int lane = tid & 63, wid = tid >> 6;
  const int wr = wid >> 1, wc = wid & 1;
  const int ro = lane & 15, hi = lane >> 4;

  f32x4 acc0[4][4], acc1[4][4];
#pragma unroll
  for (int m = 0; m < 4; m++)
#pragma unroll
    for (int n = 0; n < 4; n++) {
      acc0[m][n] = (f32x4){0.f, 0.f, 0.f, 0.f};
      acc1[m][n] = (f32x4){0.f, 0.f, 0.f, 0.f};
    }
  f32x4 vzacc[4][2];
  if (VZ) {
#pragma unroll
    for (int m = 0; m < 4; m++)
#pragma unroll
      for (int cf = 0; cf < 2; cf++) vzacc[m][cf] = (f32x4){0.f, 0.f, 0.f, 0.f};
  }

  auto stage = [&](int buf, int k0) {
    char* Ax = smem + buf * 24576;
    char* Bx = Ax + 8192;
    if (AF32) {
      const float* Af = (const float*)Ain;
#pragma unroll
      for (int it = 0; it < 2; it++) {
        const int e = (tid + it * 256) * 8;
        const int r = e >> 5, c = e & 31;
        const float* s = Af + (size_t)(m0 + r) * K + k0 + c;
        f32x4 a = *(const f32x4*)s, b = *(const f32x4*)(s + 4);
        U8 pk;
#pragma unroll
        for (int j = 0; j < 4; j++) { pk.u[j] = f2bf(a[j]); pk.u[4 + j] = f2bf(b[j]); }
        *(short8*)(Ax + ((r * 64 + c * 2) ^ swz(r))) = pk.v;
      }
    } else {
      const u16* Ab = (const u16*)Ain;
#pragma unroll
      for (int i = 0; i < 2; i++) {
        const int boff = i * 4096 + wid * 1024;
        const int t = boff + lane * 16;
        const int row = t >> 6;
        const int cb = (t & 63) ^ swz(row);
        cp16(Ab + (size_t)(m0 + row) * K + k0 + (cb >> 1), Ax + boff);
      }
    }
#pragma unroll
    for (int i = 0; i < 4; i++) {
      const int boff = i * 4096 + wid * 1024;
      const int t = boff + lane * 16;
      const int row = t >> 6;
      const int cb = (t & 63) ^ swz(row);
      cp16(W + (size_t)row * K + k0 + (cb >> 1), Bx + boff);
    }
    if (VZ) {
      // G tile 64x32 bf16 (4KB): 64-B rows, same swizzle family
      char* Gx = smem + 49152 + buf * 4096;
      const int boff = wid * 1024;
      const int t = boff + lane * 16;
      const int row = t >> 6;
      const int cb = (t & 63) ^ swz(row);
      cp16(Gw + (size_t)row * 256 + k0 + (cb >> 1), Gx + boff);
    }
  };

  auto compute = [&](int buf) {
    char* Ax = smem + buf * 24576;
    char* Bx = Ax + 8192;
    short8 af[4], fb0[4], fb1[4];
#pragma unroll
    for (int m = 0; m < 4; m++) {
      const int row = wr * 64 + m * 16 + ro;
      af[m] = *(const short8*)(Ax + ((row * 64 + hi * 16) ^ swz(row)));
    }
#pragma unroll
    for (int n = 0; n < 4; n++) {
      const int r0 = wc * 64 + n * 16 + ro;
      fb0[n] = *(const short8*)(Bx + ((r0 * 64 + hi * 16) ^ swz(r0)));
      const int r1 = 128 + r0;
      fb1[n] = *(const short8*)(Bx + ((r1 * 64 + hi * 16) ^ swz(r1)));
    }
    __builtin_amdgcn_s_setprio(1);
#pragma unroll
    for (int m = 0; m < 4; m++)
#pragma unroll
      for (int n = 0; n < 4; n++) {
        acc0[m][n] = MFMA16(af[m], fb0[n], acc0[m][n], 0, 0, 0);
        acc1[m][n] = MFMA16(af[m], fb1[n], acc1[m][n], 0, 0, 0);
      }
    if (VZ) {
      char* Gx = smem + 49152 + buf * 4096;
#pragma unroll
      for (int cf = 0; cf < 2; cf++) {
        const int row = wc * 32 + cf * 16 + ro;
        short8 gb = *(const short8*)(Gx + ((row * 64 + hi * 16) ^ swz(row)));
#pragma unroll
        for (int m = 0; m < 4; m++)
          vzacc[m][cf] = MFMA16(af[m], gb, vzacc[m][cf], 0, 0, 0);
      }
    }
    __builtin_amdgcn_s_setprio(0);
  };

  constexpr int NT = K / 32;
  if (AF32) {
    stage(0, 0);
    __syncthreads();
    int cur = 0;
    for (int k0 = 32; k0 < K; k0 += 32) {
      stage(cur ^ 1, k0);
      compute(cur);
      __syncthreads();
      cur ^= 1;
    }
    compute(cur);
    __syncthreads();
  } else {
    stage(0, 0);
    stage(1, 32);
#pragma unroll
    for (int t = 0; t < NT; ++t) {
      if (t == NT - 1)  asm volatile("s_waitcnt vmcnt(0)" ::: "memory");
      else if (VZ)      asm volatile("s_waitcnt vmcnt(7)" ::: "memory");
      else              asm volatile("s_waitcnt vmcnt(6)" ::: "memory");
      asm volatile("s_barrier" ::: "memory");
      compute(t & 1);
      asm volatile("s_barrier" ::: "memory");
      if (t + 2 < NT) stage(t & 1, (t + 2) * 32);
    }
  }

  if (VZ) {
    // transposed store Vzt[b][c][k] (verified gemmv pattern):
    // token = m0 + wr*64 + m*16 + hi*4 + j  ->  bidx = m0/64 + wr, ke = m*16+hi*4
#pragma unroll
    for (int m = 0; m < 4; m++) {
      const int bidx = (m0 >> 6) + wr;
      const int ke = m * 16 + hi * 4;
#pragma unroll
      for (int cf = 0; cf < 2; cf++) {
        const int c = wc * 32 + cf * 16 + ro;
        U4 pk;
#pragma unroll
        for (int j = 0; j < 4; j++) pk.u[j] = f2bf(vzacc[m][cf][j]);
        *(u64*)(Vzt + (size_t)bidx * 4096 + (size_t)c * 64 + ke) = pk.v;
      }
    }
  }

  u16 (*Cs)[136] = (u16(*)[136])smem;
  auto ep = [&](f32x4 (&acc)[4][4], const int n0) {
#pragma unroll
    for (int half = 0; half < 2; half++) {
      if (wr == half) {
#pragma unroll
        for (int n = 0; n < 4; n++) {
          const int col = wc * 64 + n * 16 + ro;
          const float bb = bias[n0 + col];
#pragma unroll
          for (int m = 0; m < 4; m++)
#pragma unroll
            for (int j = 0; j < 4; j++) {
              float val = acc[m][n][j] + bb;
              if (relu) val = fmaxf(val, 0.f);
              Cs[m * 16 + hi * 4 + j][col] = f2bf(val);
            }
        }
      }
      __syncthreads();
      for (int i = tid; i < 64 * 16; i += 256) {
        const int r = i >> 4, c = (i & 15) << 3;
        *(short8*)(C + (size_t)(m0 + half * 64 + r) * 256 + n0 + c) = *(short8*)&Cs[r][c];
      }
      __syncthreads();
    }
  };
  ep(acc0, 0);
  ep(acc1, 128);
}

// ---------------------------------------------------------------------------
// L2: gemm1 (blocks 0..511, K=128, AF32) + prep2 (512..527)  [R16 exact]
// ---------------------------------------------------------------------------
__global__ __launch_bounds__(256, 2) void k_gemm1_prep2(
    const float* __restrict__ obs, const u16* __restrict__ W1b,
    const float* __restrict__ b1, u16* __restrict__ x1,
    const float* __restrict__ W3, const float* __restrict__ M1,
    const float* __restrict__ bvchain, const float* __restrict__ bvw,
    float* __restrict__ Wzf, float* __restrict__ bz) {
  __shared__ char smem[49152];
  if (blockIdx.x < 512) {
    gemm_full2<128, true, false>(obs, W1b, b1, x1, (int)blockIdx.x * 128,
                                 true, smem, nullptr, nullptr);
    return;
  }
  float* w3r = (float*)smem;
  float* red = (float*)(smem + 1024);
  const int a = blockIdx.x - 512, d = threadIdx.x;
  w3r[d] = W3[a * 256 + d];
  __syncthreads();
  float acc = 0.f;
#pragma unroll 8
  for (int j = 0; j < 256; j++) acc += w3r[j] * M1[j * 256 + d];
  Wzf[a * 256 + d] = acc;
  float p = w3r[d] * bvchain[d] + acc * bvw[d];
  for (int off = 32; off >= 1; off >>= 1) p += __shfl_xor(p, off);
  if ((d & 63) == 0) red[d >> 6] = p;
  __syncthreads();
  if (d == 0) bz[a] = red[0] + red[1] + red[2] + red[3];
}

// ---------------------------------------------------------------------------
// L3: x2 (blocks 0..511) + prep3 (512..575)  [R16 exact]
// ---------------------------------------------------------------------------
__global__ __launch_bounds__(256, 2) void k_x2_prep3(
    const u16* __restrict__ x1, const u16* __restrict__ W2b,
    const float* __restrict__ b2, u16* __restrict__ x2,
    const float* __restrict__ Wzf, const float* __restrict__ Wv,
    u16* __restrict__ G) {
  __shared__ char smem[49152];
  if (blockIdx.x < 512) {
    gemm_full2<256, false, false>(x1, W2b, b2, x2, (int)blockIdx.x * 128,
                                  true, smem, nullptr, nullptr);
    return;
  }
  const int g = blockIdx.x - 512, d2 = threadIdx.x;
  const int h = g >> 4, a = g & 15;
  float* wzr = (float*)smem;
  if (d2 < 64) wzr[d2] = Wzf[a * 256 + h * 64 + d2];
  __syncthreads();
  float acc = 0.f;
#pragma unroll 8
  for (int d = 0; d < 64; d++) acc += wzr[d] * Wv[(size_t)(h * 64 + d) * 256 + d2];
  G[g * 256 + d2] = f2bf(acc);
}

// ---------------------------------------------------------------------------
// L4: Q/K full-row tiles, XCD-paired (blocks 0..1023). Q-blocks (sub=0)
// additionally compute Vz riding their staged x2 tiles (VZ=true).
// ---------------------------------------------------------------------------
__global__ __launch_bounds__(256, 2) void k_qk(
    const u16* __restrict__ x2,
    const u16* __restrict__ Wqb, const float* __restrict__ bq, u16* __restrict__ Qg,
    const u16* __restrict__ Wkb, const float* __restrict__ bk, u16* __restrict__ Kg,
    const u16* __restrict__ G, u16* __restrict__ Vzt) {
  __shared__ char smem[57344];   // 2x24KB + 2x4KB G tiles
  const int bid = blockIdx.x;
  const int q = bid >> 4, r = bid & 15;
  const int mt = q * 8 + (r & 7);
  const int sub = r >> 3;
  if (sub == 0) {
    gemm_full2<256, false, true>(x2, Wqb, bq, Qg, mt * 128, false, smem,
                                 G, Vzt);
  } else {
    gemm_full2<256, false, false>(x2, Wkb, bk, Kg, mt * 128, false, smem,
                                  nullptr, nullptr);
  }
}

// ---------------------------------------------------------------------------
// attn_fused: per b. QK^T -> masked in-register softmax -> P@Vz ->
// cross-head Z reduce -> out = adj@Z + b3 + deg*bz. adjm precomputed (L1).
// Zs overlays Ps (PV in regs + barrier): LDS 37.4 KB.
// ---------------------------------------------------------------------------
__global__ __launch_bounds__(256, 2) void attn_fused(
    const u16* __restrict__ Qg, const u16* __restrict__ Kg,
    const u16* __restrict__ Vzt, const u64* __restrict__ adjm_g,
    const float* __restrict__ bz, const float* __restrict__ b3,
    float* __restrict__ out) {
  __shared__ char sm_raw[36864];
  __shared__ u64 adjm[64];
  u16 (*Ps)[64][72] = (u16(*)[64][72])sm_raw;
  float (*Zs)[64][16] = (float(*)[64][16])sm_raw;

  const int b = blockIdx.x, tid = threadIdx.x;
  const int lane = tid & 63, w = tid >> 6;
  const int ro = lane & 15, hi = lane >> 4;
  const int hc = w * 64;
  const size_t base = (size_t)b * 64 * 256;

  if (tid < 64) adjm[tid] = adjm_g[(size_t)b * 64 + tid];

  short8 kb[4][2];
#pragma unroll
  for (int n = 0; n < 4; n++)
#pragma unroll
    for (int ks = 0; ks < 2; ks++)
      kb[n][ks] = *(const short8*)(Kg + base + (size_t)(n * 16 + ro) * 256 + hc + ks * 32 + hi * 8);

  f32x4 s[4][4];
#pragma unroll
  for (int m = 0; m < 4; m++) {
    short8 af[2];
#pragma unroll
    for (int ks = 0; ks < 2; ks++)
      af[ks] = *(const short8*)(Qg + base + (size_t)(m * 16 + ro) * 256 + hc + ks * 32 + hi * 8);
#pragma unroll
    for (int n = 0; n < 4; n++) s[m][n] = (f32x4){0.f, 0.f, 0.f, 0.f};
#pragma unroll
    for (int ks = 0; ks < 2; ks++)
#pragma unroll
      for (int n = 0; n < 4; n++)
        s[m][n] = MFMA16(af[ks], kb[n][ks], s[m][n], 0, 0, 0);
  }

  short8 vz[2];
#pragma unroll
  for (int ks = 0; ks < 2; ks++)
    vz[ks] = *(const short8*)(Vzt + (size_t)b * 4096 + (size_t)(hc / 4 + ro) * 64 + ks * 32 + hi * 8);

  __syncthreads();   // adjm ready

#pragma unroll
  for (int m = 0; m < 4; m++) {
#pragma unroll
    for (int j = 0; j < 4; j++) {
      const int q = m * 16 + hi * 4 + j;
      const u64 msk = adjm[q];
      float sv[4], ev[4];
      float mx = -3.0e38f;
#pragma unroll
      for (int n = 0; n < 4; n++) {
        const bool on = (msk >> (n * 16 + ro)) & 1ull;
        sv[n] = on ? s[m][n][j] * 0.125f : -3.0e38f;
        mx = fmaxf(mx, sv[n]);
      }
      mx = fmaxf(mx, __shfl_xor(mx, 1));
      mx = fmaxf(mx, __shfl_xor(mx, 2));
      mx = fmaxf(mx, __shfl_xor(mx, 4));
      mx = fmaxf(mx, __shfl_xor(mx, 8));
      float sum = 0.f;
#pragma unroll
      for (int n = 0; n < 4; n++) {
        ev[n] = (sv[n] > -1.0e37f) ? __expf(sv[n] - mx) : 0.f;
        sum += ev[n];
      }
      sum += __shfl_xor(sum, 1);
      sum += __shfl_xor(sum, 2);
      sum += __shfl_xor(sum, 4);
      sum += __shfl_xor(sum, 8);
      const float inv = 1.0f / sum;
#pragma unroll
      for (int n = 0; n < 4; n++)
        Ps[w][q][n * 16 + ro] = f2bf(ev[n] * inv);
    }
  }

  f32x4 oz[4];
#pragma unroll
  for (int m = 0; m < 4; m++) {
    short8 pa[2];
    pa[0] = *(const short8*)&Ps[w][m * 16 + ro][hi * 8];
    pa[1] = *(const short8*)&Ps[w][m * 16 + ro][32 + hi * 8];
    oz[m] = (f32x4){0.f, 0.f, 0.f, 0.f};
#pragma unroll
    for (int ks = 0; ks < 2; ks++)
      oz[m] = MFMA16(pa[ks], vz[ks], oz[m], 0, 0, 0);
  }
  __syncthreads();

#pragma unroll
  for (int m = 0; m < 4; m++)
#pragma unroll
    for (int j = 0; j < 4; j++)
      Zs[w][m * 16 + hi * 4 + j][ro] = oz[m][j];
  __syncthreads();

  for (int i = tid; i < 1024; i += 256) {
    const int r = i >> 4, a = i & 15;
    Zs[0][r][a] += Zs[1][r][a] + Zs[2][r][a] + Zs[3][r][a];
  }
  __syncthreads();

  {
    const int n = tid >> 2, a4 = (tid & 3) << 2;
    const u64 msk = adjm[n];
    const float deg = (float)__popcll(msk);
    float a0 = 0.f, a1 = 0.f, a2 = 0.f, a3 = 0.f;
#pragma unroll 8
    for (int m = 0; m < 64; m++) {
      const float wv = (float)((msk >> m) & 1ull);
      f32x4 z = *(const f32x4*)&Zs[0][m][a4];
      a0 += wv * z[0]; a1 += wv * z[1]; a2 += wv * z[2]; a3 += wv * z[3];
    }
    f32x4 r;
    r[0] = a0 + b3[a4 + 0] + deg * bz[a4 + 0];
    r[1] = a1 + b3[a4 + 1] + deg * bz[a4 + 1];
    r[2] = a2 + b3[a4 + 2] + deg * bz[a4 + 2];
    r[3] = a3 + b3[a4 + 3] + deg * bz[a4 + 3];
    *(f32x4*)(out + ((size_t)b * 64 + n) * 16 + a4) = r;
  }
}

// ---------------------------------------------------------------------------
extern "C" void kernel_launch(void* const* d_in, const int* in_sizes, int n_in,
                              void* d_out, int out_size, void* d_ws, size_t ws_size,
                              hipStream_t stream) {
  const float* obs = (const float*)d_in[0];
  const float* adj = (const float*)d_in[1];
  const float* W1  = (const float*)d_in[2];
  const float* b1  = (const float*)d_in[3];
  const float* W2  = (const float*)d_in[4];
  const float* b2  = (const float*)d_in[5];
  const float* Wq  = (const float*)d_in[6];
  const float* bq  = (const float*)d_in[7];
  const float* Wk  = (const float*)d_in[8];
  const float* bk  = (const float*)d_in[9];
  const float* Wv  = (const float*)d_in[10];
  const float* bvw = (const float*)d_in[11];
  const float* Wo  = (const float*)d_in[12];
  const float* bo  = (const float*)d_in[13];
  const float* Wc  = (const float*)d_in[14];
  const float* bc  = (const float*)d_in[15];
  const float* W3  = (const float*)d_in[16];
  const float* b3  = (const float*)d_in[17];
  float* out = (float*)d_out;

  char* ws = (char*)d_ws;
  const size_t BIG = (size_t)MTOT * 256 * 2;       // 33.5 MB
  u16* buf0 = (u16*)(ws);                          // x1
  u16* buf1 = (u16*)(ws + BIG);                    // x2
  u16* buf2 = (u16*)(ws + 2 * BIG);                // Q
  u16* buf3 = (u16*)(ws + 3 * BIG);                // K
  char* p = ws + 4 * BIG;
  u16* W1b = (u16*)p;              p += 128 * 256 * 2;
  u16* W2b = (u16*)p;              p += 256 * 256 * 2;
  u16* Wqb = (u16*)p;              p += 256 * 256 * 2;
  u16* Wkb = (u16*)p;              p += 256 * 256 * 2;
  float* M1 = (float*)p;           p += 256 * 256 * 4;
  float* Wzf = (float*)p;          p += 16 * 256 * 4;
  u16* G   = (u16*)p;              p += 64 * 256 * 2;
  float* bv = (float*)p;           p += 256 * 4;
  float* bz = (float*)p;           p += 16 * 4;
  u64* adjm_g = (u64*)p;           p += (size_t)MTOT * 8;        // 512 KB
  u16* Vzt = (u16*)p;              p += (size_t)MTOT * 64 * 2;   // 8.4 MB

  dim3 blk(256);
  k_l1<<<dim3(1392), blk, 0, stream>>>(Wc, Wo, bo, bc, M1, bv,
                                       W1, W2, Wq, Wk, W1b, W2b, Wqb, Wkb,
                                       adj, adjm_g);
  k_gemm1_prep2<<<dim3(528), blk, 0, stream>>>(obs, W1b, b1, buf0,
                                               W3, M1, bv, bvw, Wzf, bz);
  k_x2_prep3<<<dim3(576), blk, 0, stream>>>(buf0, W2b, b2, buf1, Wzf, Wv, G);
  k_qk<<<dim3(1024), blk, 0, stream>>>(buf1, Wqb, bq, buf2, Wkb, bk, buf3,
                                       G, Vzt);
  attn_fused<<<dim3(1024), blk, 0, stream>>>(buf2, buf3, Vzt, adjm_g, bz, b3, out);
}

// Round 20
// 118.810 us; speedup vs baseline: 1.0950x; 1.0524x over previous
//
#include <hip/hip_runtime.h>
#include <stdint.h>

typedef unsigned short u16;
typedef unsigned long long u64;
typedef __attribute__((ext_vector_type(8))) short short8;
typedef __attribute__((ext_vector_type(4))) float f32x4;

#define MFMA16 __builtin_amdgcn_mfma_f32_16x16x32_bf16

#define MTOT 65536   // B*N = 1024*64

__device__ __forceinline__ u16 f2bf(float f) {
  union { float f; uint32_t u; } v; v.f = f;
  uint32_t r = v.u + 0x7FFFu + ((v.u >> 16) & 1u);
  return (u16)(r >> 16);
}

union U8 { short8 v; u16 u[8]; };
union U4 { u64 v; u16 u[4]; };

__device__ __forceinline__ void cp16(const void* g, void* l) {
  __builtin_amdgcn_global_load_lds(
      (const __attribute__((address_space(1))) void*)g,
      (__attribute__((address_space(3))) void*)l, 16, 0, 0);
}

// 64-B-row LDS swizzle: chunk ^= (row>>1)&3
__device__ __forceinline__ int swz(int row) { return ((row >> 1) & 3) << 4; }

// ---------------------------------------------------------------------------
// L1: prep1 (0..255) + wconv W1,W2,Wq,Wk (256..367) + adj bitmask (368..1391)
// ---------------------------------------------------------------------------
__global__ __launch_bounds__(256) void k_l1(
    const float* __restrict__ Wc, const float* __restrict__ Wo,
    const float* __restrict__ bo, const float* __restrict__ bc,
    float* __restrict__ M1, float* __restrict__ bv,
    const float* __restrict__ W1, const float* __restrict__ W2,
    const float* __restrict__ Wq, const float* __restrict__ Wk,
    u16* o1, u16* o2, u16* oq, u16* ok,
    const float* __restrict__ adj, u64* __restrict__ adjm_g) {
  const int bid = blockIdx.x, tid = threadIdx.x;
  if (bid < 256) {
    __shared__ float wcr[256];
    __shared__ float red[4];
    const int j = bid, d = tid;
    wcr[d] = Wc[j * 256 + d];
    __syncthreads();
    float acc = 0.f;
    for (int i = 0; i < 256; i++) acc += wcr[i] * Wo[i * 256 + d];
    M1[j * 256 + d] = acc;
    float p = wcr[d] * bo[d];
    for (int off = 32; off >= 1; off >>= 1) p += __shfl_xor(p, off);
    if ((d & 63) == 0) red[d >> 6] = p;
    __syncthreads();
    if (d == 0) bv[j] = bc[j] + red[0] + red[1] + red[2] + red[3];
  } else if (bid < 368) {
    int off8 = (bid - 256) * 256 + tid;
    const float* src; u16* dst;
    if      (off8 <  4096) { src = W1; dst = o1; }
    else if (off8 < 12288) { src = W2; dst = o2; off8 -= 4096; }
    else if (off8 < 20480) { src = Wq; dst = oq; off8 -= 12288; }
    else                   { src = Wk; dst = ok; off8 -= 20480; }
    const int e = off8 * 8;
    f32x4 a = *(const f32x4*)(src + e);
    f32x4 b = *(const f32x4*)(src + e + 4);
    U8 pk;
#pragma unroll
    for (int j = 0; j < 4; j++) { pk.u[j] = f2bf(a[j]); pk.u[4 + j] = f2bf(b[j]); }
    *(short8*)(dst + e) = pk.v;
  } else {
    __shared__ u16 chunk[64][4];
    const int b = bid - 368;
    const int q = tid >> 2, qa = tid & 3;
    const float* ar = adj + ((size_t)b * 64 + q) * 64 + qa * 16;
    f32x4 a0 = *(const f32x4*)(ar);
    f32x4 a1 = *(const f32x4*)(ar + 4);
    f32x4 a2 = *(const f32x4*)(ar + 8);
    f32x4 a3 = *(const f32x4*)(ar + 12);
    unsigned m16 = 0;
#pragma unroll
    for (int i = 0; i < 4; i++) {
      m16 |= (unsigned)(a0[i] != 0.f) << i;
      m16 |= (unsigned)(a1[i] != 0.f) << (4 + i);
      m16 |= (unsigned)(a2[i] != 0.f) << (8 + i);
      m16 |= (unsigned)(a3[i] != 0.f) << (12 + i);
    }
    chunk[q][qa] = (u16)m16;
    __syncthreads();
    if (tid < 64)
      adjm_g[(size_t)b * 64 + tid] =
          (u64)chunk[tid][0] | ((u64)chunk[tid][1] << 16) |
          ((u64)chunk[tid][2] << 32) | ((u64)chunk[tid][3] << 48);
  }
}

// ---------------------------------------------------------------------------
// gemm_full2<K,AF32>: C[m0:+128, 0:256] = act(A[M,K] @ W[256,K]^T + b) -> bf16
// BK=32 dbuf; non-AF32 counted-vmcnt pipeline; AF32 plain barrier loop.
// LDS-staged coalesced epilogue. [R11/R14-verified structure — do NOT
// tighten launch_bounds: 128 acc VGPRs spill below (256,2) (R6, R15).]
// ---------------------------------------------------------------------------
template<int K, bool AF32>
__device__ __forceinline__ void gemm_full2(
    const void* __restrict__ Ain, const u16* __restrict__ W,
    const float* __restrict__ bias, u16* __restrict__ C,
    const int m0, const bool relu, char* smem) {
  const int tid = threadIdx.x;
  const int lane = tid & 63, wid = tid >> 6;
  const int wr = wid >> 1, wc = wid & 1;
  const int ro = lane & 15, hi = lane >> 4;

  f32x4 acc0[4][4], acc1[4][4];
#pragma unroll
  for (int m = 0; m < 4; m++)
#pragma unroll
    for (int n = 0; n < 4; n++) {
      acc0[m][n] = (f32x4){0.f, 0.f, 0.f, 0.f};
      acc1[m][n] = (f32x4){0.f, 0.f, 0.f, 0.f};
    }

  auto stage = [&](int buf, int k0) {
    char* Ax = smem + buf * 24576;
    char* Bx = Ax + 8192;
    if (AF32) {
      const float* Af = (const float*)Ain;
#pragma unroll
      for (int it = 0; it < 2; it++) {
        const int e = (tid + it * 256) * 8;
        const int r = e >> 5, c = e & 31;
        const float* s = Af + (size_t)(m0 + r) * K + k0 + c;
        f32x4 a = *(const f32x4*)s, b = *(const f32x4*)(s + 4);
        U8 pk;
#pragma unroll
        for (int j = 0; j < 4; j++) { pk.u[j] = f2bf(a[j]); pk.u[4 + j] = f2bf(b[j]); }
        *(short8*)(Ax + ((r * 64 + c * 2) ^ swz(r))) = pk.v;
      }
    } else {
      const u16* Ab = (const u16*)Ain;
#pragma unroll
      for (int i = 0; i < 2; i++) {
        const int boff = i * 4096 + wid * 1024;
        const int t = boff + lane * 16;
        const int row = t >> 6;
        const int cb = (t & 63) ^ swz(row);
        cp16(Ab + (size_t)(m0 + row) * K + k0 + (cb >> 1), Ax + boff);
      }
    }
#pragma unroll
    for (int i = 0; i < 4; i++) {
      const int boff = i * 4096 + wid * 1024;
      const int t = boff + lane * 16;
      const int row = t >> 6;
      const int cb = (t & 63) ^ swz(row);
      cp16(W + (size_t)row * K + k0 + (cb >> 1), Bx + boff);
    }
  };

  auto compute = [&](int buf) {
    char* Ax = smem + buf * 24576;
    char* Bx = Ax + 8192;
    short8 af[4], fb0[4], fb1[4];
#pragma unroll
    for (int m = 0; m < 4; m++) {
      const int row = wr * 64 + m * 16 + ro;
      af[m] = *(const short8*)(Ax + ((row * 64 + hi * 16) ^ swz(row)));
    }
#pragma unroll
    for (int n = 0; n < 4; n++) {
      const int r0 = wc * 64 + n * 16 + ro;
      fb0[n] = *(const short8*)(Bx + ((r0 * 64 + hi * 16) ^ swz(r0)));
      const int r1 = 128 + r0;
      fb1[n] = *(const short8*)(Bx + ((r1 * 64 + hi * 16) ^ swz(r1)));
    }
    __builtin_amdgcn_s_setprio(1);
#pragma unroll
    for (int m = 0; m < 4; m++)
#pragma unroll
      for (int n = 0; n < 4; n++) {
        acc0[m][n] = MFMA16(af[m], fb0[n], acc0[m][n], 0, 0, 0);
        acc1[m][n] = MFMA16(af[m], fb1[n], acc1[m][n], 0, 0, 0);
      }
    __builtin_amdgcn_s_setprio(0);
  };

  constexpr int NT = K / 32;
  if (AF32) {
    stage(0, 0);
    __syncthreads();
    int cur = 0;
    for (int k0 = 32; k0 < K; k0 += 32) {
      stage(cur ^ 1, k0);
      compute(cur);
      __syncthreads();
      cur ^= 1;
    }
    compute(cur);
    __syncthreads();
  } else {
    stage(0, 0);
    stage(1, 32);
#pragma unroll
    for (int t = 0; t < NT; ++t) {
      if (t == NT - 1) asm volatile("s_waitcnt vmcnt(0)" ::: "memory");
      else             asm volatile("s_waitcnt vmcnt(6)" ::: "memory");
      asm volatile("s_barrier" ::: "memory");
      compute(t & 1);
      asm volatile("s_barrier" ::: "memory");
      if (t + 2 < NT) stage(t & 1, (t + 2) * 32);
    }
  }

  u16 (*Cs)[136] = (u16(*)[136])smem;
  auto ep = [&](f32x4 (&acc)[4][4], const int n0) {
#pragma unroll
    for (int half = 0; half < 2; half++) {
      if (wr == half) {
#pragma unroll
        for (int n = 0; n < 4; n++) {
          const int col = wc * 64 + n * 16 + ro;
          const float bb = bias[n0 + col];
#pragma unroll
          for (int m = 0; m < 4; m++)
#pragma unroll
            for (int j = 0; j < 4; j++) {
              float val = acc[m][n][j] + bb;
              if (relu) val = fmaxf(val, 0.f);
              Cs[m * 16 + hi * 4 + j][col] = f2bf(val);
            }
        }
      }
      __syncthreads();
      for (int i = tid; i < 64 * 16; i += 256) {
        const int r = i >> 4, c = (i & 15) << 3;
        *(short8*)(C + (size_t)(m0 + half * 64 + r) * 256 + n0 + c) = *(short8*)&Cs[r][c];
      }
      __syncthreads();
    }
  };
  ep(acc0, 0);
  ep(acc1, 128);
}

// ---------------------------------------------------------------------------
// L2: gemm1 (blocks 0..511, K=128, AF32) + prep2 (512..527)
// ---------------------------------------------------------------------------
__global__ __launch_bounds__(256, 2) void k_gemm1_prep2(
    const float* __restrict__ obs, const u16* __restrict__ W1b,
    const float* __restrict__ b1, u16* __restrict__ x1,
    const float* __restrict__ W3, const float* __restrict__ M1,
    const float* __restrict__ bvchain, const float* __restrict__ bvw,
    float* __restrict__ Wzf, float* __restrict__ bz) {
  __shared__ char smem[49152];
  if (blockIdx.x < 512) {
    gemm_full2<128, true>(obs, W1b, b1, x1, (int)blockIdx.x * 128, true, smem);
    return;
  }
  float* w3r = (float*)smem;
  float* red = (float*)(smem + 1024);
  const int a = blockIdx.x - 512, d = threadIdx.x;
  w3r[d] = W3[a * 256 + d];
  __syncthreads();
  float acc = 0.f;
  for (int j = 0; j < 256; j++) acc += w3r[j] * M1[j * 256 + d];
  Wzf[a * 256 + d] = acc;
  float p = w3r[d] * bvchain[d] + acc * bvw[d];
  for (int off = 32; off >= 1; off >>= 1) p += __shfl_xor(p, off);
  if ((d & 63) == 0) red[d >> 6] = p;
  __syncthreads();
  if (d == 0) bz[a] = red[0] + red[1] + red[2] + red[3];
}

// ---------------------------------------------------------------------------
// L3: x2 (blocks 0..511) + prep3 (512..575)
// ---------------------------------------------------------------------------
__global__ __launch_bounds__(256, 2) void k_x2_prep3(
    const u16* __restrict__ x1, const u16* __restrict__ W2b,
    const float* __restrict__ b2, u16* __restrict__ x2,
    const float* __restrict__ Wzf, const float* __restrict__ Wv,
    u16* __restrict__ G) {
  __shared__ char smem[49152];
  if (blockIdx.x < 512) {
    gemm_full2<256, false>(x1, W2b, b2, x2, (int)blockIdx.x * 128, true, smem);
    return;
  }
  const int g = blockIdx.x - 512, d2 = threadIdx.x;
  const int h = g >> 4, a = g & 15;
  float* wzr = (float*)smem;
  if (d2 < 64) wzr[d2] = Wzf[a * 256 + h * 64 + d2];
  __syncthreads();
  float acc = 0.f;
#pragma unroll 8
  for (int d = 0; d < 64; d++) acc += wzr[d] * Wv[(size_t)(h * 64 + d) * 256 + d2];
  G[g * 256 + d2] = f2bf(acc);
}

// ---------------------------------------------------------------------------
// L4: Q/K full-row tiles, XCD-paired (blocks 0..1023) + gemmv counted-vmcnt
// pipeline (1024..1535)  [R14 exact]
// ---------------------------------------------------------------------------
__global__ __launch_bounds__(256, 2) void k_qk_gemmv(
    const u16* __restrict__ x2,
    const u16* __restrict__ Wqb, const float* __restrict__ bq, u16* __restrict__ Qg,
    const u16* __restrict__ Wkb, const float* __restrict__ bk, u16* __restrict__ Kg,
    const u16* __restrict__ G, u16* __restrict__ Vzt) {
  __shared__ char smem[49152];
  const int bid = blockIdx.x;
  if (bid < 1024) {
    const int q = bid >> 4, r = bid & 15;
    const int mt = q * 8 + (r & 7);
    const int sub = r >> 3;
    gemm_full2<256, false>(x2, sub ? Wkb : Wqb, sub ? bk : bq, sub ? Kg : Qg,
                           mt * 128, false, smem);
    return;
  }
  const int tid = threadIdx.x;
  const int lane = tid & 63, w = tid >> 6;
  const int ro = lane & 15, hi = lane >> 4;
  const int m0 = (bid - 1024) * 128;

  f32x4 acc[2][4];
#pragma unroll
  for (int m = 0; m < 2; m++)
#pragma unroll
    for (int n = 0; n < 4; n++) acc[m][n] = (f32x4){0.f, 0.f, 0.f, 0.f};

  auto stage = [&](int buf, int k0) {
    char* Ax = smem + buf * 12288;
    char* Bx = Ax + 8192;
#pragma unroll
    for (int i = 0; i < 2; i++) {
      const int boff = i * 4096 + w * 1024;
      const int t = boff + lane * 16;
      const int row = t >> 6;
      const int cb = (t & 63) ^ swz(row);
      cp16(x2 + (size_t)(m0 + row) * 256 + k0 + (cb >> 1), Ax + boff);
    }
    {
      const int boff = w * 1024;
      const int t = boff + lane * 16;
      const int row = t >> 6;
      const int cb = (t & 63) ^ swz(row);
      cp16(G + (size_t)row * 256 + k0 + (cb >> 1), Bx + boff);
    }
  };
  auto compute = [&](int buf) {
    char* Ax = smem + buf * 12288;
    char* Bx = Ax + 8192;
    short8 af[2], fb[4];
#pragma unroll
    for (int m = 0; m < 2; m++) {
      const int row = w * 32 + m * 16 + ro;
      af[m] = *(const short8*)(Ax + ((row * 64 + hi * 16) ^ swz(row)));
    }
#pragma unroll
    for (int n = 0; n < 4; n++) {
      const int row = n * 16 + ro;
      fb[n] = *(const short8*)(Bx + ((row * 64 + hi * 16) ^ swz(row)));
    }
    __builtin_amdgcn_s_setprio(1);
#pragma unroll
    for (int m = 0; m < 2; m++)
#pragma unroll
      for (int n = 0; n < 4; n++)
        acc[m][n] = MFMA16(af[m], fb[n], acc[m][n], 0, 0, 0);
    __builtin_amdgcn_s_setprio(0);
  };

  stage(0, 0);
  stage(1, 32);
#pragma unroll
  for (int t = 0; t < 8; ++t) {
    if (t == 7) asm volatile("s_waitcnt vmcnt(0)" ::: "memory");
    else        asm volatile("s_waitcnt vmcnt(3)" ::: "memory");
    asm volatile("s_barrier" ::: "memory");
    compute(t & 1);
    asm volatile("s_barrier" ::: "memory");
    if (t + 2 < 8) stage(t & 1, (t + 2) * 32);
  }

#pragma unroll
  for (int m = 0; m < 2; m++) {
    const int rbase = w * 32 + m * 16;
    const int bidx = (m0 >> 6) + (rbase >> 6);
    const int ke = (rbase + hi * 4) & 63;
#pragma unroll
    for (int n = 0; n < 4; n++) {
      const int c = n * 16 + ro;
      U4 pk;
#pragma unroll
      for (int j = 0; j < 4; j++) pk.u[j] = f2bf(acc[m][n][j]);
      *(u64*)(Vzt + (size_t)bidx * 4096 + (size_t)c * 64 + ke) = pk.v;
    }
  }
}

// ---------------------------------------------------------------------------
// attn_fused: per b. QK^T -> masked in-register softmax -> P@Vz ->
// cross-head Z reduce -> out = adj@Z + b3 + deg*bz. adjm precomputed (L1).
// Zs OVERLAYS Ps (PV outputs in regs + barrier): LDS 37.4 KB.
// launch_bounds kept at (256,2) — regalloc untouched (R15 lesson).
// ---------------------------------------------------------------------------
__global__ __launch_bounds__(256, 2) void attn_fused(
    const u16* __restrict__ Qg, const u16* __restrict__ Kg,
    const u16* __restrict__ Vzt, const u64* __restrict__ adjm_g,
    const float* __restrict__ bz, const float* __restrict__ b3,
    float* __restrict__ out) {
  __shared__ char sm_raw[36864];          // Ps[4][64][72] u16; later Zs[4][64][16] f32
  __shared__ u64 adjm[64];
  u16 (*Ps)[64][72] = (u16(*)[64][72])sm_raw;
  float (*Zs)[64][16] = (float(*)[64][16])sm_raw;

  const int b = blockIdx.x, tid = threadIdx.x;
  const int lane = tid & 63, w = tid >> 6;
  const int ro = lane & 15, hi = lane >> 4;
  const int hc = w * 64;
  const size_t base = (size_t)b * 64 * 256;

  if (tid < 64) adjm[tid] = adjm_g[(size_t)b * 64 + tid];

  short8 kb[4][2];
#pragma unroll
  for (int n = 0; n < 4; n++)
#pragma unroll
    for (int ks = 0; ks < 2; ks++)
      kb[n][ks] = *(const short8*)(Kg + base + (size_t)(n * 16 + ro) * 256 + hc + ks * 32 + hi * 8);

  f32x4 s[4][4];
#pragma unroll
  for (int m = 0; m < 4; m++) {
    short8 af[2];
#pragma unroll
    for (int ks = 0; ks < 2; ks++)
      af[ks] = *(const short8*)(Qg + base + (size_t)(m * 16 + ro) * 256 + hc + ks * 32 + hi * 8);
#pragma unroll
    for (int n = 0; n < 4; n++) s[m][n] = (f32x4){0.f, 0.f, 0.f, 0.f};
#pragma unroll
    for (int ks = 0; ks < 2; ks++)
#pragma unroll
      for (int n = 0; n < 4; n++)
        s[m][n] = MFMA16(af[ks], kb[n][ks], s[m][n], 0, 0, 0);
  }

  short8 vz[2];
#pragma unroll
  for (int ks = 0; ks < 2; ks++)
    vz[ks] = *(const short8*)(Vzt + (size_t)b * 4096 + (size_t)(hc / 4 + ro) * 64 + ks * 32 + hi * 8);

  __syncthreads();   // adjm ready

#pragma unroll
  for (int m = 0; m < 4; m++) {
#pragma unroll
    for (int j = 0; j < 4; j++) {
      const int q = m * 16 + hi * 4 + j;
      const u64 msk = adjm[q];
      float sv[4], ev[4];
      float mx = -3.0e38f;
#pragma unroll
      for (int n = 0; n < 4; n++) {
        const bool on = (msk >> (n * 16 + ro)) & 1ull;
        sv[n] = on ? s[m][n][j] * 0.125f : -3.0e38f;
        mx = fmaxf(mx, sv[n]);
      }
      mx = fmaxf(mx, __shfl_xor(mx, 1));
      mx = fmaxf(mx, __shfl_xor(mx, 2));
      mx = fmaxf(mx, __shfl_xor(mx, 4));
      mx = fmaxf(mx, __shfl_xor(mx, 8));
      float sum = 0.f;
#pragma unroll
      for (int n = 0; n < 4; n++) {
        ev[n] = (sv[n] > -1.0e37f) ? __expf(sv[n] - mx) : 0.f;
        sum += ev[n];
      }
      sum += __shfl_xor(sum, 1);
      sum += __shfl_xor(sum, 2);
      sum += __shfl_xor(sum, 4);
      sum += __shfl_xor(sum, 8);
      const float inv = 1.0f / sum;
#pragma unroll
      for (int n = 0; n < 4; n++)
        Ps[w][q][n * 16 + ro] = f2bf(ev[n] * inv);
    }
  }
  // own-wave DS ordering: Ps[w] writes retire before own reads below

  // PV into registers (Ps still live)
  f32x4 oz[4];
#pragma unroll
  for (int m = 0; m < 4; m++) {
    short8 pa[2];
    pa[0] = *(const short8*)&Ps[w][m * 16 + ro][hi * 8];
    pa[1] = *(const short8*)&Ps[w][m * 16 + ro][32 + hi * 8];
    oz[m] = (f32x4){0.f, 0.f, 0.f, 0.f};
#pragma unroll
    for (int ks = 0; ks < 2; ks++)
      oz[m] = MFMA16(pa[ks], vz[ks], oz[m], 0, 0, 0);
  }
  __syncthreads();   // all Ps reads done -> safe to overlay Zs

#pragma unroll
  for (int m = 0; m < 4; m++)
#pragma unroll
    for (int j = 0; j < 4; j++)
      Zs[w][m * 16 + hi * 4 + j][ro] = oz[m][j];
  __syncthreads();

  for (int i = tid; i < 1024; i += 256) {
    const int r = i >> 4, a = i & 15;
    Zs[0][r][a] += Zs[1][r][a] + Zs[2][r][a] + Zs[3][r][a];
  }
  __syncthreads();

  {
    const int n = tid >> 2, a4 = (tid & 3) << 2;
    const u64 msk = adjm[n];
    const float deg = (float)__popcll(msk);
    float a0 = 0.f, a1 = 0.f, a2 = 0.f, a3 = 0.f;
#pragma unroll 8
    for (int m = 0; m < 64; m++) {
      const float wv = (float)((msk >> m) & 1ull);
      f32x4 z = *(const f32x4*)&Zs[0][m][a4];
      a0 += wv * z[0]; a1 += wv * z[1]; a2 += wv * z[2]; a3 += wv * z[3];
    }
    f32x4 r;
    r[0] = a0 + b3[a4 + 0] + deg * bz[a4 + 0];
    r[1] = a1 + b3[a4 + 1] + deg * bz[a4 + 1];
    r[2] = a2 + b3[a4 + 2] + deg * bz[a4 + 2];
    r[3] = a3 + b3[a4 + 3] + deg * bz[a4 + 3];
    *(f32x4*)(out + ((size_t)b * 64 + n) * 16 + a4) = r;
  }
}

// ---------------------------------------------------------------------------
extern "C" void kernel_launch(void* const* d_in, const int* in_sizes, int n_in,
                              void* d_out, int out_size, void* d_ws, size_t ws_size,
                              hipStream_t stream) {
  const float* obs = (const float*)d_in[0];
  const float* adj = (const float*)d_in[1];
  const float* W1  = (const float*)d_in[2];
  const float* b1  = (const float*)d_in[3];
  const float* W2  = (const float*)d_in[4];
  const float* b2  = (const float*)d_in[5];
  const float* Wq  = (const float*)d_in[6];
  const float* bq  = (const float*)d_in[7];
  const float* Wk  = (const float*)d_in[8];
  const float* bk  = (const float*)d_in[9];
  const float* Wv  = (const float*)d_in[10];
  const float* bvw = (const float*)d_in[11];
  const float* Wo  = (const float*)d_in[12];
  const float* bo  = (const float*)d_in[13];
  const float* Wc  = (const float*)d_in[14];
  const float* bc  = (const float*)d_in[15];
  const float* W3  = (const float*)d_in[16];
  const float* b3  = (const float*)d_in[17];
  float* out = (float*)d_out;

  char* ws = (char*)d_ws;
  const size_t BIG = (size_t)MTOT * 256 * 2;       // 33.5 MB
  u16* buf0 = (u16*)(ws);                          // x1, then Vzt (x1 dead)
  u16* buf1 = (u16*)(ws + BIG);                    // x2
  u16* buf2 = (u16*)(ws + 2 * BIG);                // Q
  u16* buf3 = (u16*)(ws + 3 * BIG);                // K
  char* p = ws + 4 * BIG;
  u16* W1b = (u16*)p;              p += 128 * 256 * 2;
  u16* W2b = (u16*)p;              p += 256 * 256 * 2;
  u16* Wqb = (u16*)p;              p += 256 * 256 * 2;
  u16* Wkb = (u16*)p;              p += 256 * 256 * 2;
  float* M1 = (float*)p;           p += 256 * 256 * 4;
  float* Wzf = (float*)p;          p += 16 * 256 * 4;
  u16* G   = (u16*)p;              p += 64 * 256 * 2;
  float* bv = (float*)p;           p += 256 * 4;
  float* bz = (float*)p;           p += 16 * 4;
  u64* adjm_g = (u64*)p;           p += (size_t)MTOT * 8;   // 512 KB

  dim3 blk(256);
  k_l1<<<dim3(1392), blk, 0, stream>>>(Wc, Wo, bo, bc, M1, bv,
                                       W1, W2, Wq, Wk, W1b, W2b, Wqb, Wkb,
                                       adj, adjm_g);
  k_gemm1_prep2<<<dim3(528), blk, 0, stream>>>(obs, W1b, b1, buf0,
                                               W3, M1, bv, bvw, Wzf, bz);
  k_x2_prep3<<<dim3(576), blk, 0, stream>>>(buf0, W2b, b2, buf1, Wzf, Wv, G);
  k_qk_gemmv<<<dim3(1536), blk, 0, stream>>>(buf1, Wqb, bq, buf2,
                                             Wkb, bk, buf3, G, buf0);
  attn_fused<<<dim3(1024), blk, 0, stream>>>(buf2, buf3, buf0, adjm_g, bz, b3, out);
}